// Round 3
// baseline (507.162 us; speedup 1.0000x reference)
//
#include <hip/hip_runtime.h>
#include <hip/hip_bf16.h>
#include <math.h>

#define B_   64
#define T_   32
#define S_   31      // scan steps = T-1
#define V_   10000
#define E_   300
#define H_   256
#define F_   4096
#define G4   1024    // 4*H
#define HE   556     // H+E
#define MPAD 2048    // S_*B_ = 1984 padded to 2048
#define NPAD 10112   // V padded to 79*128
#define START_ID 1
#define NBL  4       // k_lstm blocks: batch-partitioned, fully independent

typedef __bf16 bf16x8 __attribute__((ext_vector_type(8)));
typedef float  f32x4  __attribute__((ext_vector_type(4)));

__device__ __forceinline__ float bf16bits_to_f(unsigned int u) {
    union { unsigned int i; float f; } c; c.i = u; return c.f;
}
__device__ __forceinline__ unsigned short f_to_bf16bits(float f) {
    union { float f; unsigned int i; } c; c.f = f;
    unsigned int r = c.i + 0x7fffu + ((c.i >> 16) & 1);   // RNE
    return (unsigned short)(r >> 16);
}
__device__ __forceinline__ float sigm(float x) { return 1.f / (1.f + __expf(-x)); }
__device__ __forceinline__ float tanh_fast(float x) { return 1.f - 2.f / (__expf(2.f * x) + 1.f); }

// ---------------- prep: fc2_w -> bf16 (pad rows zeroed), zero Hs pad rows, zero Xp
__global__ void k_prep(const float* __restrict__ fc2_w,
                       __hip_bfloat16* __restrict__ fc2bf,
                       __hip_bfloat16* __restrict__ Hs,
                       float* __restrict__ Xp) {
    size_t i = (size_t)blockIdx.x * 256 + threadIdx.x;   // < NPAD*H_
    float v = (i < (size_t)V_ * H_) ? fc2_w[i] : 0.f;
    fc2bf[i] = __float2bfloat16(v);
    if (i < (size_t)(MPAD - S_ * B_) * H_)
        Hs[(size_t)S_ * B_ * H_ + i] = __float2bfloat16(0.f);
    if (i < B_ * H_) Xp[i] = 0.f;
}

// ---------------- pack w_hh into MFMA A-fragment-linear bf16 (frag-major)
// frag = (w*8 + nt)*8 + kf ; lane (l16,quad): j = (l16&3)*256 + w*32 + nt*4 + (l16>>2),
// k0 = kf*32 + quad*8 ; wpack[frag*512 + lane*8 .. +8] = bf16(w_hh[j][k0..k0+8])
__global__ void k_wpack(const float* __restrict__ w_hh, unsigned short* __restrict__ wpack) {
    int tid = blockIdx.x * 256 + threadIdx.x;   // < 32768
    int lane = tid & 63, frag = tid >> 6;       // frag < 512
    int kf = frag & 7, nt = (frag >> 3) & 7, w = frag >> 6;
    int l16 = lane & 15, quad = lane >> 4;
    int j = (l16 & 3) * 256 + w * 32 + nt * 4 + (l16 >> 2);
    int k0 = kf * 32 + quad * 8;
    const float* src = w_hh + (size_t)j * H_ + k0;
    float4 a0 = *(const float4*)(src);
    float4 a1 = *(const float4*)(src + 4);
    unsigned short pk[8];
    pk[0] = f_to_bf16bits(a0.x); pk[1] = f_to_bf16bits(a0.y);
    pk[2] = f_to_bf16bits(a0.z); pk[3] = f_to_bf16bits(a0.w);
    pk[4] = f_to_bf16bits(a1.x); pk[5] = f_to_bf16bits(a1.y);
    pk[6] = f_to_bf16bits(a1.z); pk[7] = f_to_bf16bits(a1.w);
    uint4 st;
    st.x = (unsigned)pk[0] | ((unsigned)pk[1] << 16);
    st.y = (unsigned)pk[2] | ((unsigned)pk[3] << 16);
    st.z = (unsigned)pk[4] | ((unsigned)pk[5] << 16);
    st.w = (unsigned)pk[6] | ((unsigned)pk[7] << 16);
    *(uint4*)(wpack + (size_t)frag * 512 + lane * 8) = st;
}

// ---------------- one-hot rows at t=0
__global__ void k_onehot(float* __restrict__ out) {
    int i = blockIdx.x * 256 + threadIdx.x;
    if (i < B_ * V_) {
        int b = i / V_, v = i - b * V_;
        out[(size_t)b * T_ * V_ + v] = (v == START_ID) ? 1.f : 0.f;
    }
}

// ---------------- Xp = X @ fc1_w.T + fc1_b   (64 x 256), K split 4-ways
__global__ void k_xp(const float* __restrict__ X, const float* __restrict__ fc1_w,
                     const float* __restrict__ fc1_b, float* __restrict__ Xp) {
    __shared__ __align__(16) float xs[1024];
    int b = blockIdx.x, q = blockIdx.y;          // q = K-chunk of 1024
    const float4* xrow = (const float4*)(X + (size_t)b * F_ + q * 1024);
    if (threadIdx.x < 256) ((float4*)xs)[threadIdx.x] = xrow[threadIdx.x];
    __syncthreads();
    int k = threadIdx.x;
    const float4* w = (const float4*)(fc1_w + (size_t)k * F_ + q * 1024);
    float acc = 0.f;
    #pragma unroll 8
    for (int f = 0; f < 256; ++f) {
        float4 wv = w[f];
        float4 xv = ((const float4*)xs)[f];
        acc += wv.x * xv.x + wv.y * xv.y + wv.z * xv.z + wv.w * xv.w;
    }
    if (q == 0) acc += fc1_b[k];
    atomicAdd(&Xp[b * H_ + k], acc);
}

// ---------------- gconst = Xp @ w_ih[:, :H].T + b_ih + b_hh   (64 x 1024)
__global__ void k_gconst(const float* __restrict__ Xp, const float* __restrict__ w_ih,
                         const float* __restrict__ b_ih, const float* __restrict__ b_hh,
                         float* __restrict__ gconst) {
    __shared__ __align__(16) float xs[H_];
    int b = blockIdx.x;
    xs[threadIdx.x] = Xp[b * H_ + threadIdx.x];
    __syncthreads();
    #pragma unroll
    for (int q = 0; q < 4; ++q) {
        int j = threadIdx.x + q * 256;
        const float* w = w_ih + (size_t)j * HE;
        float acc = 0.f;
        #pragma unroll 8
        for (int k = 0; k < H_ / 4; ++k) {
            float4 wv = *(const float4*)(w + k * 4);
            float4 xv = ((const float4*)xs)[k];
            acc += wv.x * xv.x + wv.y * xv.y + wv.z * xv.z + wv.w * xv.w;
        }
        gconst[b * G4 + j] = acc + b_ih[j] + b_hh[j];
    }
}

// ---------------- gfullT: per (t, bg=b>>4) tile grid [tile=u>>2][b_local 16][m 16]
// m = (u&3)*4 + gate  (matches k_lstm MFMA C layout: acc[r] = gate r directly)
__global__ void k_ge(const float* __restrict__ emb, const int* __restrict__ label,
                     const float* __restrict__ w_ih, const float* __restrict__ gconst,
                     unsigned short* __restrict__ gfullT) {
    __shared__ __align__(16) float es[8][E_];
    int jt = blockIdx.x, bt = blockIdx.y, t = blockIdx.z;
    for (int i = threadIdx.x; i < 8 * E_; i += 256) {
        int b8 = i / E_, e = i - b8 * E_;
        int b = bt * 8 + b8;
        int idx = (t == 0) ? START_ID : label[t * B_ + b];
        es[b8][e] = emb[(size_t)idx * E_ + e];
    }
    __syncthreads();
    int j = jt * 256 + threadIdx.x;               // gate = jt, u = threadIdx.x
    const float* w = w_ih + (size_t)j * HE + H_;
    float acc[8] = {0.f, 0.f, 0.f, 0.f, 0.f, 0.f, 0.f, 0.f};
    for (int kk = 0; kk < E_ / 4; ++kk) {
        float4 wv = *(const float4*)(w + kk * 4);
        #pragma unroll
        for (int b8 = 0; b8 < 8; ++b8) {
            float4 ev = *(const float4*)(&es[b8][kk * 4]);
            acc[b8] += wv.x * ev.x + wv.y * ev.y + wv.z * ev.z + wv.w * ev.w;
        }
    }
    int u = threadIdx.x;
    int tile = u >> 2;                            // = w*8 + nt
    int m = (u & 3) * 4 + jt;
    size_t base = ((((size_t)t * NBL + (bt >> 1)) * 64 + tile) * 16 + (bt & 1) * 8) * 16 + m;
    #pragma unroll
    for (int b8 = 0; b8 < 8; ++b8)
        gfullT[base + (size_t)b8 * 16] =
            f_to_bf16bits(acc[b8] + gconst[(bt * 8 + b8) * G4 + j]);
}

// ---------------- LSTM recurrence: 4 independent blocks x 512 thr, 16 batches each.
// NO inter-block communication: h lives in LDS for all 31 steps. Per wave: 8 n-tiles
// (hidden [w*32,w*32+32)); w_hh frags: nt0-1 registers, nt2-3 LDS, nt4-7 streamed
// from L2-resident wpack each step. Round-3 schedule: all stream+gf loads issued
// right AFTER the mid-step barrier (avoids the barrier's vmcnt(0) drain), pinned
// above compute with sched_barrier(0) so they cannot be sunk to their use point;
// gf add deferred to tile end so its load has the MFMA chain to hide under.
__global__ __launch_bounds__(512, 2) void k_lstm(const unsigned short* __restrict__ gfullT,
                                                 const unsigned short* __restrict__ wpack,
                                                 __hip_bfloat16* __restrict__ Hs_) {
    unsigned short* Hs = (unsigned short*)Hs_;
    int bg = blockIdx.x;
    int tid = threadIdx.x;
    int w = tid >> 6, lane = tid & 63;
    int l16 = lane & 15, quad = lane >> 4;

    // h: [16 batches][264] (8-short pad -> row stride 132 dwords == 4 mod 32:
    // the 16-row x 528B-stride ds_read_b128 pattern is (near) conflict-free)
    __shared__ __align__(16) unsigned short hs[16 * 264];          // 8448 B
    __shared__ __align__(16) unsigned short blds[8 * 16 * 64 * 8]; // 128 KiB

    // persistent register weights: nt 0,1 (A-frags)
    const unsigned short* wpb = wpack + (size_t)(w * 8) * 8 * 512 + lane * 8;
    bf16x8 wr0[8], wr1[8];
    #pragma unroll
    for (int kf = 0; kf < 8; ++kf) wr0[kf] = *(const bf16x8*)(wpb + (0 * 8 + kf) * 512);
    #pragma unroll
    for (int kf = 0; kf < 8; ++kf) wr1[kf] = *(const bf16x8*)(wpb + (1 * 8 + kf) * 512);

    // LDS weights: nt 2,3  (linear layout -> conflict-free b128)
    #pragma unroll
    for (int f2 = 0; f2 < 16; ++f2) {
        int nt = 2 + (f2 >> 3), kf = f2 & 7;
        bf16x8 v = *(const bf16x8*)(wpb + (nt * 8 + kf) * 512);
        *(bf16x8*)(blds + ((size_t)(w * 16 + f2) * 64 + lane) * 8) = v;
    }

    // h(-1) = 0
    for (int i = tid; i < 16 * 264 / 8; i += 512)
        ((uint4*)hs)[i] = make_uint4(0, 0, 0, 0);
    __syncthreads();

    float c[8] = {0.f, 0.f, 0.f, 0.f, 0.f, 0.f, 0.f, 0.f};
    const unsigned short* bl = blds + (size_t)(w * 16) * 512 + lane * 8;
    const unsigned short* hb = hs + l16 * 264 + quad * 8;
    int orow = tid >> 5, ocol = tid & 31;   // Hs writeout mapping

    for (int t = 0; t < S_; ++t) {
        // -------- all hs reads for this step (h(t-1)), before it is overwritten
        bf16x8 hf[8];
        #pragma unroll
        for (int kf = 0; kf < 8; ++kf) hf[kf] = *(const bf16x8*)(hb + kf * 32);
        uint4 wv = make_uint4(0u, 0u, 0u, 0u);
        if (t > 0) wv = *(const uint4*)(hs + orow * 264 + ocol * 8);
        __syncthreads();   // all hs reads done before any new-h writes below

        // -------- issue L2 streams (nt4,5,6) + gate consts, pinned above compute
        bf16x8 sA[8], sB[8], sC[8];
        #pragma unroll
        for (int kf = 0; kf < 8; ++kf) sA[kf] = *(const bf16x8*)(wpb + (4 * 8 + kf) * 512);
        #pragma unroll
        for (int kf = 0; kf < 8; ++kf) sB[kf] = *(const bf16x8*)(wpb + (5 * 8 + kf) * 512);
        #pragma unroll
        for (int kf = 0; kf < 8; ++kf) sC[kf] = *(const bf16x8*)(wpb + (6 * 8 + kf) * 512);
        uint2 gf[8];
        const unsigned short* gtb = gfullT +
            ((((size_t)t * NBL + bg) * 64 + w * 8) * 256) + l16 * 16 + quad * 4;
        #pragma unroll
        for (int nt = 0; nt < 8; ++nt) gf[nt] = *(const uint2*)(gtb + nt * 256);
        // previous step's h -> Hs (coalesced; data read from LDS above)
        if (t > 0)
            *(uint4*)(Hs + ((size_t)((t - 1) * B_ + bg * 16 + orow)) * H_ + ocol * 8) = wv;
        __builtin_amdgcn_sched_barrier(0);   // loads stay issued above this point

#define DO_NT(nt, WSRC)                                                         \
        {                                                                       \
            f32x4 acc = {0.f, 0.f, 0.f, 0.f};                                   \
            _Pragma("unroll")                                                   \
            for (int kf = 0; kf < 8; ++kf)                                      \
                acc = __builtin_amdgcn_mfma_f32_16x16x32_bf16(WSRC[kf], hf[kf], \
                                                              acc, 0, 0, 0);   \
            float g0 = acc[0] + bf16bits_to_f(gf[nt].x << 16);                  \
            float g1 = acc[1] + bf16bits_to_f(gf[nt].x & 0xffff0000u);          \
            float g2 = acc[2] + bf16bits_to_f(gf[nt].y << 16);                  \
            float g3 = acc[3] + bf16bits_to_f(gf[nt].y & 0xffff0000u);          \
            float ig = sigm(g0);                                                \
            float fg = sigm(g1);                                                \
            float gg = tanh_fast(g2);                                           \
            float og = sigm(g3);                                                \
            c[nt] = fg * c[nt] + ig * gg;                                       \
            float hv = og * tanh_fast(c[nt]);                                   \
            hs[l16 * 264 + w * 32 + (nt) * 4 + quad] = f_to_bf16bits(hv);       \
        }

        DO_NT(0, wr0)
        DO_NT(1, wr1)
        {
            bf16x8 w2[8];
            #pragma unroll
            for (int kf = 0; kf < 8; ++kf) w2[kf] = *(const bf16x8*)(bl + kf * 512);
            DO_NT(2, w2)
        }
        {
            bf16x8 w3[8];
            #pragma unroll
            for (int kf = 0; kf < 8; ++kf) w3[kf] = *(const bf16x8*)(bl + (8 + kf) * 512);
            DO_NT(3, w3)
        }
        DO_NT(4, sA)
        bf16x8 sD[8];
        #pragma unroll
        for (int kf = 0; kf < 8; ++kf) sD[kf] = *(const bf16x8*)(wpb + (7 * 8 + kf) * 512);
        DO_NT(5, sB)
        DO_NT(6, sC)
        DO_NT(7, sD)
#undef DO_NT
        __syncthreads();   // new h complete before next step's reads
    }
    // final step's h
    {
        uint4 v = *(const uint4*)(hs + orow * 264 + ocol * 8);
        *(uint4*)(Hs + ((size_t)((S_ - 1) * B_ + bg * 16 + orow)) * H_ + ocol * 8) = v;
    }
}

// ---------------- logits = Hs @ fc2_w.T + fc2_b -> out[b][t+1][v]  (bf16 MFMA)
__global__ __launch_bounds__(256) void k_gemm(const unsigned short* __restrict__ A,   // MPAD x 256 bf16
                                              const unsigned short* __restrict__ Bw,  // NPAD x 256 bf16
                                              const float* __restrict__ bias,
                                              float* __restrict__ out) {
    int nt = blockIdx.x, mt = blockIdx.y;
    int w = threadIdx.x >> 6, lane = threadIdx.x & 63;
    int l16 = lane & 15, quad = lane >> 4;
    int m0 = mt * 128 + (w >> 1) * 64;
    int n0 = nt * 128 + (w & 1) * 64;
    f32x4 acc[4][4] = {};
    const unsigned short* Ap = A + (size_t)(m0 + l16) * H_ + quad * 8;
    const unsigned short* Bp = Bw + (size_t)(n0 + l16) * H_ + quad * 8;
    #pragma unroll
    for (int k = 0; k < H_; k += 32) {
        bf16x8 a[4], bb[4];
        #pragma unroll
        for (int i = 0; i < 4; ++i) {
            a[i]  = *(const bf16x8*)(Ap + (size_t)i * 16 * H_ + k);
            bb[i] = *(const bf16x8*)(Bp + (size_t)i * 16 * H_ + k);
        }
        #pragma unroll
        for (int i = 0; i < 4; ++i)
            #pragma unroll
            for (int jn = 0; jn < 4; ++jn)
                acc[i][jn] = __builtin_amdgcn_mfma_f32_16x16x32_bf16(a[i], bb[jn], acc[i][jn], 0, 0, 0);
    }
    #pragma unroll
    for (int i = 0; i < 4; ++i) {
        #pragma unroll
        for (int jn = 0; jn < 4; ++jn) {
            #pragma unroll
            for (int r = 0; r < 4; ++r) {
                int m = m0 + i * 16 + quad * 4 + r;
                int n = n0 + jn * 16 + l16;
                if (m < S_ * B_ && n < V_) {
                    int t = m >> 6, b = m & 63;
                    out[((size_t)b * T_ + t + 1) * V_ + n] = acc[i][jn][r] + bias[n];
                }
            }
        }
    }
}

// ---------------- in-place log_softmax over V per (t,b) row — online 2-pass, float4
__global__ void k_lsm(float* __restrict__ out) {
    __shared__ float rmx[256], rsum[256];
    int m = blockIdx.x;                   // 0..1983, m = t*64+b
    int t = m >> 6, b = m & 63;
    float* row = out + ((size_t)b * T_ + t + 1) * V_;
    int tid = threadIdx.x;
    float mx = -1e30f, sum = 0.f;
    for (int v4 = tid; v4 < V_ / 4; v4 += 256) {
        float4 x = ((const float4*)row)[v4];
        float m4 = fmaxf(fmaxf(x.x, x.y), fmaxf(x.z, x.w));
        if (m4 > mx) { sum *= __expf(mx - m4); mx = m4; }
        sum += __expf(x.x - mx) + __expf(x.y - mx) + __expf(x.z - mx) + __expf(x.w - mx);
    }
    rmx[tid] = mx; rsum[tid] = sum;
    __syncthreads();
    for (int s = 128; s > 0; s >>= 1) {
        if (tid < s) {
            float ma = rmx[tid], mb = rmx[tid + s];
            float sa = rsum[tid], sb = rsum[tid + s];
            float mm = fmaxf(ma, mb);
            rmx[tid] = mm;
            rsum[tid] = sa * __expf(ma - mm) + sb * __expf(mb - mm);
        }
        __syncthreads();
    }
    float lse = rmx[0] + logf(rsum[0]);
    for (int v4 = tid; v4 < V_ / 4; v4 += 256) {
        float4 x = ((const float4*)row)[v4];
        x.x -= lse; x.y -= lse; x.z -= lse; x.w -= lse;
        ((float4*)row)[v4] = x;
    }
}

extern "C" void kernel_launch(void* const* d_in, const int* in_sizes, int n_in,
                              void* d_out, int out_size, void* d_ws, size_t ws_size,
                              hipStream_t stream) {
    const float* X      = (const float*)d_in[0];
    const float* emb    = (const float*)d_in[1];
    const float* fc1_w  = (const float*)d_in[2];
    const float* fc1_b  = (const float*)d_in[3];
    const float* w_ih   = (const float*)d_in[4];
    const float* w_hh   = (const float*)d_in[5];
    const float* b_ih   = (const float*)d_in[6];
    const float* b_hh   = (const float*)d_in[7];
    const float* fc2_w  = (const float*)d_in[8];
    const float* fc2_b  = (const float*)d_in[9];
    const int*   label  = (const int*)d_in[10];
    float* out = (float*)d_out;

    char* ws = (char*)d_ws;
    float*          Xp     = (float*)(ws);                        // 65,536
    float*          gconst = (float*)(ws + 65536);                // 262,144
    unsigned short* gfullT = (unsigned short*)(ws + 327680);      // 31*4*64*256*2 = 4,063,232
    __hip_bfloat16* Hs     = (__hip_bfloat16*)(ws + 4390912);     // 2048*256*2 = 1,048,576
    __hip_bfloat16* fc2bf  = (__hip_bfloat16*)(ws + 5439488);     // 10112*256*2 = 5,177,344
    unsigned short* wpack  = (unsigned short*)(ws + 10616832);    // 512*512*2 = 524,288
    // total = 11,141,120 bytes (< proven 14.68 MB budget)

    k_prep  <<<NPAD, 256, 0, stream>>>(fc2_w, fc2bf, Hs, Xp);
    k_wpack <<<128, 256, 0, stream>>>(w_hh, wpack);
    k_onehot<<<(B_ * V_ + 255) / 256, 256, 0, stream>>>(out);
    k_xp    <<<dim3(B_, 4), 256, 0, stream>>>(X, fc1_w, fc1_b, Xp);
    k_gconst<<<B_, 256, 0, stream>>>(Xp, w_ih, b_ih, b_hh, gconst);
    k_ge    <<<dim3(4, 8, S_), 256, 0, stream>>>(emb, label, w_ih, gconst, gfullT);
    k_lstm  <<<NBL, 512, 0, stream>>>(gfullT, wpack, Hs);
    k_gemm  <<<dim3(NPAD / 128, MPAD / 128), 256, 0, stream>>>((const unsigned short*)Hs,
                                                              (const unsigned short*)fc2bf, fc2_b, out);
    k_lsm   <<<S_ * B_, 256, 0, stream>>>(out);
}

// Round 4
// 473.395 us; speedup vs baseline: 1.0713x; 1.0713x over previous
//
#include <hip/hip_runtime.h>
#include <hip/hip_bf16.h>
#include <math.h>

#define B_   64
#define T_   32
#define S_   31      // scan steps = T-1
#define V_   10000
#define E_   300
#define H_   256
#define F_   4096
#define G4   1024    // 4*H
#define HE   556     // H+E
#define MPAD 2048    // S_*B_ = 1984 padded to 2048
#define NPAD 10112   // V padded to 79*128
#define START_ID 1
#define NBL  4       // k_lstm blocks: batch-partitioned, fully independent

// k_front block-range offsets
#define FP0 10112              // prep (fc2bf cvt, Hs pad zero)
#define FP1 (FP0 + 128)        // wpack
#define FP2 (FP1 + 2500)       // onehot
#define FP3 (FP2 + 512)        // xp partials (64 b x 8 q)
#define FP4 (FP3 + 300)        // wie pack (w_ih[:,H:] -> [75][1024] float4)

typedef __bf16 bf16x8 __attribute__((ext_vector_type(8)));
typedef float  f32x4  __attribute__((ext_vector_type(4)));

__device__ __forceinline__ float bf16bits_to_f(unsigned int u) {
    union { unsigned int i; float f; } c; c.i = u; return c.f;
}
__device__ __forceinline__ unsigned short f_to_bf16bits(float f) {
    union { float f; unsigned int i; } c; c.f = f;
    unsigned int r = c.i + 0x7fffu + ((c.i >> 16) & 1);   // RNE
    return (unsigned short)(r >> 16);
}
__device__ __forceinline__ float sigm(float x) { return 1.f / (1.f + __expf(-x)); }
__device__ __forceinline__ float tanh_fast(float x) { return 1.f - 2.f / (__expf(2.f * x) + 1.f); }

// ---------------- k_front: all input-only preprocessing in ONE launch.
// Sub-grids (branch on blockIdx.x): prep | wpack | onehot | xp-partials | wie-pack.
// No cross-block dependencies inside (xp writes per-(q,b) partial slots, no atomics).
__global__ void k_front(const float* __restrict__ fc2_w,
                        __hip_bfloat16* __restrict__ fc2bf,
                        __hip_bfloat16* __restrict__ Hs,
                        const float* __restrict__ w_hh,
                        unsigned short* __restrict__ wpack,
                        float* __restrict__ out,
                        const float* __restrict__ X,
                        const float* __restrict__ fc1_w,
                        const float* __restrict__ fc1_b,
                        float* __restrict__ Xp_part,
                        const float* __restrict__ w_ih,
                        float* __restrict__ wie) {
    int bid = blockIdx.x, tid = threadIdx.x;
    if (bid < FP0) {
        // ---- prep: fc2_w -> bf16 (pad rows zeroed), zero Hs pad rows
        size_t i = (size_t)bid * 256 + tid;                  // < NPAD*H_
        float v = (i < (size_t)V_ * H_) ? fc2_w[i] : 0.f;
        fc2bf[i] = __float2bfloat16(v);
        if (i < (size_t)(MPAD - S_ * B_) * H_)
            Hs[(size_t)S_ * B_ * H_ + i] = __float2bfloat16(0.f);
    } else if (bid < FP1) {
        // ---- wpack: w_hh -> MFMA A-fragment-linear bf16 (frag-major)
        int t = (bid - FP0) * 256 + tid;                     // < 32768
        int lane = t & 63, frag = t >> 6;                    // frag < 512
        int kf = frag & 7, nt = (frag >> 3) & 7, w = frag >> 6;
        int l16 = lane & 15, quad = lane >> 4;
        int j = (l16 & 3) * 256 + w * 32 + nt * 4 + (l16 >> 2);
        int k0 = kf * 32 + quad * 8;
        const float* src = w_hh + (size_t)j * H_ + k0;
        float4 a0 = *(const float4*)(src);
        float4 a1 = *(const float4*)(src + 4);
        unsigned short pk[8];
        pk[0] = f_to_bf16bits(a0.x); pk[1] = f_to_bf16bits(a0.y);
        pk[2] = f_to_bf16bits(a0.z); pk[3] = f_to_bf16bits(a0.w);
        pk[4] = f_to_bf16bits(a1.x); pk[5] = f_to_bf16bits(a1.y);
        pk[6] = f_to_bf16bits(a1.z); pk[7] = f_to_bf16bits(a1.w);
        uint4 st;
        st.x = (unsigned)pk[0] | ((unsigned)pk[1] << 16);
        st.y = (unsigned)pk[2] | ((unsigned)pk[3] << 16);
        st.z = (unsigned)pk[4] | ((unsigned)pk[5] << 16);
        st.w = (unsigned)pk[6] | ((unsigned)pk[7] << 16);
        *(uint4*)(wpack + (size_t)frag * 512 + lane * 8) = st;
    } else if (bid < FP2) {
        // ---- one-hot rows at t=0
        int i = (bid - FP1) * 256 + tid;
        if (i < B_ * V_) {
            int b = i / V_, v = i - b * V_;
            out[(size_t)b * T_ * V_ + v] = (v == START_ID) ? 1.f : 0.f;
        }
    } else if (bid < FP3) {
        // ---- Xp partials: chunk q (512 wide) of row b -> Xp_part[q][b][k]
        __shared__ __align__(16) float xs[512];
        int r = bid - FP2;
        int b = r >> 3, q = r & 7;
        const float4* xrow = (const float4*)(X + (size_t)b * F_ + q * 512);
        if (tid < 128) ((float4*)xs)[tid] = xrow[tid];
        __syncthreads();
        int k = tid;
        const float4* w = (const float4*)(fc1_w + (size_t)k * F_ + q * 512);
        float acc = 0.f;
        #pragma unroll 8
        for (int f = 0; f < 128; ++f) {
            float4 wv = w[f];
            float4 xv = ((const float4*)xs)[f];
            acc += wv.x * xv.x + wv.y * xv.y + wv.z * xv.z + wv.w * xv.w;
        }
        if (q == 0) acc += fc1_b[k];
        Xp_part[((size_t)(q * 64 + b)) * 256 + k] = acc;
    } else if (bid < FP4) {
        // ---- wie pack: w_ih[j][H + kk*4 ..+4] -> wie[kk][j] (float4), coalesced reads in k_ge
        int idx = (bid - FP3) * 256 + tid;                   // < 76800 = 75*1024
        int kk = idx >> 10, j = idx & 1023;
        float4 v = *(const float4*)(w_ih + (size_t)j * HE + H_ + kk * 4);
        ((float4*)wie)[(size_t)kk * 1024 + j] = v;
    }
}

// ---------------- gconst = Xp @ w_ih[:, :H].T + b_ih + b_hh   (64 x 1024)
__global__ void k_gconst(const float* __restrict__ Xp_part, const float* __restrict__ w_ih,
                         const float* __restrict__ b_ih, const float* __restrict__ b_hh,
                         float* __restrict__ gconst) {
    __shared__ __align__(16) float xs[H_];
    int b = blockIdx.x;
    float s = 0.f;
    #pragma unroll
    for (int q = 0; q < 8; ++q) s += Xp_part[((size_t)(q * 64 + b)) * 256 + threadIdx.x];
    xs[threadIdx.x] = s;
    __syncthreads();
    #pragma unroll
    for (int q = 0; q < 4; ++q) {
        int j = threadIdx.x + q * 256;
        const float* w = w_ih + (size_t)j * HE;
        float acc = 0.f;
        #pragma unroll 8
        for (int k = 0; k < H_ / 4; ++k) {
            float4 wv = *(const float4*)(w + k * 4);
            float4 xv = ((const float4*)xs)[k];
            acc += wv.x * xv.x + wv.y * xv.y + wv.z * xv.z + wv.w * xv.w;
        }
        gconst[b * G4 + j] = acc + b_ih[j] + b_hh[j];
    }
}

// ---------------- gfullT: per (t, bg=b>>4) tile grid [tile=u>>2][b_local 16][m 16]
// m = (u&3)*4 + gate  (matches k_lstm MFMA C layout: acc[r] = gate r directly)
// weight reads now coalesced via wie[kk][j] pack.
__global__ void k_ge(const float* __restrict__ emb, const int* __restrict__ label,
                     const float* __restrict__ wie, const float* __restrict__ gconst,
                     unsigned short* __restrict__ gfullT) {
    __shared__ __align__(16) float es[8][E_];
    int jt = blockIdx.x, bt = blockIdx.y, t = blockIdx.z;
    for (int i = threadIdx.x; i < 8 * E_; i += 256) {
        int b8 = i / E_, e = i - b8 * E_;
        int b = bt * 8 + b8;
        int idx = (t == 0) ? START_ID : label[t * B_ + b];
        es[b8][e] = emb[(size_t)idx * E_ + e];
    }
    __syncthreads();
    int j = jt * 256 + threadIdx.x;               // gate = jt, u = threadIdx.x
    const float4* wp4 = (const float4*)wie + j;   // stride 1024 float4 per kk
    float acc[8] = {0.f, 0.f, 0.f, 0.f, 0.f, 0.f, 0.f, 0.f};
    for (int kk = 0; kk < E_ / 4; ++kk) {
        float4 wv = wp4[(size_t)kk * 1024];
        #pragma unroll
        for (int b8 = 0; b8 < 8; ++b8) {
            float4 ev = *(const float4*)(&es[b8][kk * 4]);
            acc[b8] += wv.x * ev.x + wv.y * ev.y + wv.z * ev.z + wv.w * ev.w;
        }
    }
    int u = threadIdx.x;
    int tile = u >> 2;                            // = w*8 + nt
    int m = (u & 3) * 4 + jt;
    size_t base = ((((size_t)t * NBL + (bt >> 1)) * 64 + tile) * 16 + (bt & 1) * 8) * 16 + m;
    #pragma unroll
    for (int b8 = 0; b8 < 8; ++b8)
        gfullT[base + (size_t)b8 * 16] =
            f_to_bf16bits(acc[b8] + gconst[(bt * 8 + b8) * G4 + j]);
}

// ---------------- LSTM recurrence: 4 independent blocks x 512 thr, 16 batches each.
// NO inter-block communication: h lives in LDS for all 31 steps. Per wave: 8 n-tiles
// (hidden [w*32,w*32+32)). Weight split (round 4): tiles 0-3 REGISTERS (128 VGPR),
// tiles 4-5 LDS, tiles 6-7 streamed from L2 (128 KB/step/CU, half of round 2).
// amdgpu_waves_per_eu(2,2) tells the allocator occupancy >2 waves/EU is useless,
// freeing the full 256-VGPR budget so the persistent tiles are not sunk to re-loads.
__global__ __launch_bounds__(512)
__attribute__((amdgpu_waves_per_eu(2, 2)))
void k_lstm(const unsigned short* __restrict__ gfullT,
            const unsigned short* __restrict__ wpack,
            __hip_bfloat16* __restrict__ Hs_) {
    unsigned short* Hs = (unsigned short*)Hs_;
    int bg = blockIdx.x;
    int tid = threadIdx.x;
    int w = tid >> 6, lane = tid & 63;
    int l16 = lane & 15, quad = lane >> 4;

    // h: [16 batches][264] (8-short pad -> row stride 132 dwords == 4 mod 32:
    // the 16-row x 528B-stride ds_read_b128 pattern is (near) conflict-free)
    __shared__ __align__(16) unsigned short hs[16 * 264];          // 8448 B
    __shared__ __align__(16) unsigned short blds[8 * 16 * 64 * 8]; // 128 KiB (tiles 4,5)

    // persistent register weights: tiles 0-3 (A-frags)
    const unsigned short* wpb = wpack + (size_t)(w * 8) * 8 * 512 + lane * 8;
    bf16x8 wr0[8], wr1[8], wr2[8], wr3[8];
    #pragma unroll
    for (int kf = 0; kf < 8; ++kf) wr0[kf] = *(const bf16x8*)(wpb + (0 * 8 + kf) * 512);
    #pragma unroll
    for (int kf = 0; kf < 8; ++kf) wr1[kf] = *(const bf16x8*)(wpb + (1 * 8 + kf) * 512);
    #pragma unroll
    for (int kf = 0; kf < 8; ++kf) wr2[kf] = *(const bf16x8*)(wpb + (2 * 8 + kf) * 512);
    #pragma unroll
    for (int kf = 0; kf < 8; ++kf) wr3[kf] = *(const bf16x8*)(wpb + (3 * 8 + kf) * 512);

    // LDS weights: tiles 4,5  (linear layout -> conflict-free b128)
    #pragma unroll
    for (int f2 = 0; f2 < 16; ++f2) {
        int nt = 4 + (f2 >> 3), kf = f2 & 7;
        bf16x8 v = *(const bf16x8*)(wpb + (nt * 8 + kf) * 512);
        *(bf16x8*)(blds + ((size_t)(w * 16 + f2) * 64 + lane) * 8) = v;
    }

    // h(-1) = 0
    for (int i = tid; i < 16 * 264 / 8; i += 512)
        ((uint4*)hs)[i] = make_uint4(0, 0, 0, 0);
    __syncthreads();

    float c[8] = {0.f, 0.f, 0.f, 0.f, 0.f, 0.f, 0.f, 0.f};
    const unsigned short* bl = blds + (size_t)(w * 16) * 512 + lane * 8;
    const unsigned short* hb = hs + l16 * 264 + quad * 8;
    int orow = tid >> 5, ocol = tid & 31;   // Hs writeout mapping

    for (int t = 0; t < S_; ++t) {
        // -------- previous h -> Hs (read from LDS before it is overwritten)
        if (t > 0) {
            uint4 wv = *(const uint4*)(hs + orow * 264 + ocol * 8);
            *(uint4*)(Hs + ((size_t)((t - 1) * B_ + bg * 16 + orow)) * H_ + ocol * 8) = wv;
        }
        // gate-constant C-init tiles (L2/IF$ resident)
        uint2 gf[8];
        const unsigned short* gtb = gfullT +
            ((((size_t)t * NBL + bg) * 64 + w * 8) * 256) + l16 * 16 + quad * 4;
        #pragma unroll
        for (int nt = 0; nt < 8; ++nt) gf[nt] = *(const uint2*)(gtb + nt * 256);
        // h B-fragments for this step
        bf16x8 hf[8];
        #pragma unroll
        for (int kf = 0; kf < 8; ++kf) hf[kf] = *(const bf16x8*)(hb + kf * 32);
        __syncthreads();   // all hs reads done before any new-h writes below

        // stream tile 6 now (overlaps tiles 0-5 compute; consumed at DO_NT(6))
        bf16x8 s6[8];
        #pragma unroll
        for (int kf = 0; kf < 8; ++kf) s6[kf] = *(const bf16x8*)(wpb + (6 * 8 + kf) * 512);

#define DO_NT(nt, WSRC)                                                         \
        {                                                                       \
            f32x4 acc;                                                          \
            acc[0] = bf16bits_to_f(gf[nt].x << 16);                             \
            acc[1] = bf16bits_to_f(gf[nt].x & 0xffff0000u);                     \
            acc[2] = bf16bits_to_f(gf[nt].y << 16);                             \
            acc[3] = bf16bits_to_f(gf[nt].y & 0xffff0000u);                     \
            _Pragma("unroll")                                                   \
            for (int kf = 0; kf < 8; ++kf)                                      \
                acc = __builtin_amdgcn_mfma_f32_16x16x32_bf16(WSRC[kf], hf[kf], \
                                                              acc, 0, 0, 0);   \
            float ig = sigm(acc[0]);                                            \
            float fg = sigm(acc[1]);                                            \
            float gg = tanh_fast(acc[2]);                                       \
            float og = sigm(acc[3]);                                            \
            c[nt] = fg * c[nt] + ig * gg;                                       \
            float hv = og * tanh_fast(c[nt]);                                   \
            hs[l16 * 264 + w * 32 + (nt) * 4 + quad] = f_to_bf16bits(hv);       \
        }

        DO_NT(0, wr0)
        DO_NT(1, wr1)
        DO_NT(2, wr2)
        DO_NT(3, wr3)
        {
            bf16x8 w4[8];
            #pragma unroll
            for (int kf = 0; kf < 8; ++kf) w4[kf] = *(const bf16x8*)(bl + kf * 512);
            DO_NT(4, w4)
        }
        // stream tile 7 (consumed after tile 6's compute)
        bf16x8 s7[8];
        #pragma unroll
        for (int kf = 0; kf < 8; ++kf) s7[kf] = *(const bf16x8*)(wpb + (7 * 8 + kf) * 512);
        {
            bf16x8 w5[8];
            #pragma unroll
            for (int kf = 0; kf < 8; ++kf) w5[kf] = *(const bf16x8*)(bl + (8 + kf) * 512);
            DO_NT(5, w5)
        }
        DO_NT(6, s6)
        DO_NT(7, s7)
#undef DO_NT
        __syncthreads();   // new h complete before next step's reads
    }
    // final step's h
    {
        uint4 v = *(const uint4*)(hs + orow * 264 + ocol * 8);
        *(uint4*)(Hs + ((size_t)((S_ - 1) * B_ + bg * 16 + orow)) * H_ + ocol * 8) = v;
    }
}

// ---------------- logits = Hs @ fc2_w.T + fc2_b -> out[b][t+1][v]  (bf16 MFMA)
__global__ __launch_bounds__(256) void k_gemm(const unsigned short* __restrict__ A,   // MPAD x 256 bf16
                                              const unsigned short* __restrict__ Bw,  // NPAD x 256 bf16
                                              const float* __restrict__ bias,
                                              float* __restrict__ out) {
    int nt = blockIdx.x, mt = blockIdx.y;
    int w = threadIdx.x >> 6, lane = threadIdx.x & 63;
    int l16 = lane & 15, quad = lane >> 4;
    int m0 = mt * 128 + (w >> 1) * 64;
    int n0 = nt * 128 + (w & 1) * 64;
    f32x4 acc[4][4] = {};
    const unsigned short* Ap = A + (size_t)(m0 + l16) * H_ + quad * 8;
    const unsigned short* Bp = Bw + (size_t)(n0 + l16) * H_ + quad * 8;
    #pragma unroll
    for (int k = 0; k < H_; k += 32) {
        bf16x8 a[4], bb[4];
        #pragma unroll
        for (int i = 0; i < 4; ++i) {
            a[i]  = *(const bf16x8*)(Ap + (size_t)i * 16 * H_ + k);
            bb[i] = *(const bf16x8*)(Bp + (size_t)i * 16 * H_ + k);
        }
        #pragma unroll
        for (int i = 0; i < 4; ++i)
            #pragma unroll
            for (int jn = 0; jn < 4; ++jn)
                acc[i][jn] = __builtin_amdgcn_mfma_f32_16x16x32_bf16(a[i], bb[jn], acc[i][jn], 0, 0, 0);
    }
    #pragma unroll
    for (int i = 0; i < 4; ++i) {
        #pragma unroll
        for (int jn = 0; jn < 4; ++jn) {
            #pragma unroll
            for (int r = 0; r < 4; ++r) {
                int m = m0 + i * 16 + quad * 4 + r;
                int n = n0 + jn * 16 + l16;
                if (m < S_ * B_ && n < V_) {
                    int t = m >> 6, b = m & 63;
                    out[((size_t)b * T_ + t + 1) * V_ + n] = acc[i][jn][r] + bias[n];
                }
            }
        }
    }
}

// ---------------- in-place log_softmax over V per (t,b) row — LDS-staged single
// global read + single global write (saves the 2nd 79MB read pass)
__global__ __launch_bounds__(256) void k_lsm(float* __restrict__ out) {
    __shared__ __align__(16) float rowbuf[V_];   // 40000 B
    __shared__ float rmx[256], rsum[256];
    int m = blockIdx.x;                   // 0..1983, m = t*64+b
    int t = m >> 6, b = m & 63;
    float* row = out + ((size_t)b * T_ + t + 1) * V_;
    int tid = threadIdx.x;
    float mx = -1e30f, sum = 0.f;
    for (int v4 = tid; v4 < V_ / 4; v4 += 256) {
        float4 x = ((const float4*)row)[v4];
        ((float4*)rowbuf)[v4] = x;
        float m4 = fmaxf(fmaxf(x.x, x.y), fmaxf(x.z, x.w));
        if (m4 > mx) { sum *= __expf(mx - m4); mx = m4; }
        sum += __expf(x.x - mx) + __expf(x.y - mx) + __expf(x.z - mx) + __expf(x.w - mx);
    }
    rmx[tid] = mx; rsum[tid] = sum;
    __syncthreads();
    for (int s = 128; s > 0; s >>= 1) {
        if (tid < s) {
            float ma = rmx[tid], mb = rmx[tid + s];
            float sa = rsum[tid], sb = rsum[tid + s];
            float mm = fmaxf(ma, mb);
            rmx[tid] = mm;
            rsum[tid] = sa * __expf(ma - mm) + sb * __expf(mb - mm);
        }
        __syncthreads();
    }
    float lse = rmx[0] + logf(rsum[0]);
    for (int v4 = tid; v4 < V_ / 4; v4 += 256) {
        float4 x = ((const float4*)rowbuf)[v4];
        x.x -= lse; x.y -= lse; x.z -= lse; x.w -= lse;
        ((float4*)row)[v4] = x;
    }
}

extern "C" void kernel_launch(void* const* d_in, const int* in_sizes, int n_in,
                              void* d_out, int out_size, void* d_ws, size_t ws_size,
                              hipStream_t stream) {
    const float* X      = (const float*)d_in[0];
    const float* emb    = (const float*)d_in[1];
    const float* fc1_w  = (const float*)d_in[2];
    const float* fc1_b  = (const float*)d_in[3];
    const float* w_ih   = (const float*)d_in[4];
    const float* w_hh   = (const float*)d_in[5];
    const float* b_ih   = (const float*)d_in[6];
    const float* b_hh   = (const float*)d_in[7];
    const float* fc2_w  = (const float*)d_in[8];
    const float* fc2_b  = (const float*)d_in[9];
    const int*   label  = (const int*)d_in[10];
    float* out = (float*)d_out;

    char* ws = (char*)d_ws;
    float*          Xp_part = (float*)(ws);                        // 8*64*256*4 = 524,288
    float*          gconst  = (float*)(ws + 524288);               // 262,144
    unsigned short* gfullT  = (unsigned short*)(ws + 786432);      // 31*4*64*256*2 = 4,063,232
    __hip_bfloat16* Hs      = (__hip_bfloat16*)(ws + 4849664);     // 2048*256*2 = 1,048,576
    __hip_bfloat16* fc2bf   = (__hip_bfloat16*)(ws + 5898240);     // 10112*256*2 = 5,177,344
    unsigned short* wpack   = (unsigned short*)(ws + 11075584);    // 512*512*2 = 524,288
    float*          wie     = (float*)(ws + 11599872);             // 75*1024*16 = 1,228,800
    // total = 12,828,672 bytes (< proven 14.68 MB budget)

    k_front <<<FP4, 256, 0, stream>>>(fc2_w, fc2bf, Hs, w_hh, wpack, out,
                                      X, fc1_w, fc1_b, Xp_part, w_ih, wie);
    k_gconst<<<B_, 256, 0, stream>>>(Xp_part, w_ih, b_ih, b_hh, gconst);
    k_ge    <<<dim3(4, 8, S_), 256, 0, stream>>>(emb, label, wie, gconst, gfullT);
    k_lstm  <<<NBL, 512, 0, stream>>>(gfullT, wpack, Hs);
    k_gemm  <<<dim3(NPAD / 128, MPAD / 128), 256, 0, stream>>>((const unsigned short*)Hs,
                                                              (const unsigned short*)fc2bf, fc2_b, out);
    k_lsm   <<<S_ * B_, 256, 0, stream>>>(out);
}